// Round 3
// baseline (87.531 us; speedup 1.0000x reference)
//
#include <hip/hip_runtime.h>

// Problem constants
#define FDIM 256
#define BDIM 32
#define MDIM 32768
#define NB   512        // m-tiles (64 m each); one partial per (b, tile)

// ws layout (float units)
#define WS_EM    0                       // (unused after fusion; kept for layout stability)
#define WS_EX    (WS_EM + MDIM*FDIM)
#define WS_W2N   (WS_EX + BDIM*FDIM)
#define WS_PMAX  (WS_W2N + FDIM)
#define WS_PSUM  (WS_PMAX + BDIM*NB)
#define WS_PARG  (WS_PSUM + BDIM*NB)
#define WS_WIN   (WS_PARG + BDIM*NB)
#define WS_BEST  (WS_WIN + 32)
#define WS_GMAX  (WS_BEST + 32)
#define WS_GSUM  (WS_GMAX + 32)
#define WS_GARG  (WS_GSUM + 32)
#define WS_WH    (WS_GARG + 32)          // W1m hi: 65536 bf16
#define WS_WL    (WS_WH + 32768)         // W1m lo

#define C2 2.8853900817779268f   // 2*log2(e): e^{2x} = 2^(C2*x)

typedef __attribute__((ext_vector_type(8))) short bf16x8;
typedef __attribute__((ext_vector_type(8))) unsigned short ushort8;
typedef __attribute__((ext_vector_type(4))) float f32x4;

__device__ inline unsigned short f2bf(float x) {      // RNE f32 -> bf16
  unsigned u = __float_as_uint(x);
  return (unsigned short)((u + 0x7fffu + ((u >> 16) & 1u)) >> 16);
}
__device__ inline float bf2f(unsigned short h) {
  return __uint_as_float(((unsigned)h) << 16);
}

// K1: blocks 0..31: Ex[b][f] = 2^(C2*(b1[f] + sum_k input[b][k]*W1[f*512+k])); w2n = -2*W2
//     blocks 32..95: split W1m into bf16 hi/lo arrays
__global__ __launch_bounds__(256) void k1_prep(const float* __restrict__ input,
                                               const float* __restrict__ W1,
                                               const float* __restrict__ b1,
                                               const float* __restrict__ W2,
                                               float* __restrict__ Ex,
                                               float* __restrict__ w2n,
                                               unsigned short* __restrict__ wh,
                                               unsigned short* __restrict__ wl) {
  if (blockIdx.x < BDIM) {
    const int b = blockIdx.x, f = threadIdx.x;
    const float* in = input + b * FDIM;
    const float* w  = W1 + (size_t)f * 512;
    float acc = b1[f];
    #pragma unroll 8
    for (int k = 0; k < FDIM; k += 4) {
      float4 iv = *(const float4*)(in + k);
      float4 wv = *(const float4*)(w + k);
      acc = fmaf(iv.x, wv.x, acc); acc = fmaf(iv.y, wv.y, acc);
      acc = fmaf(iv.z, wv.z, acc); acc = fmaf(iv.w, wv.w, acc);
    }
    Ex[b * FDIM + f] = __builtin_amdgcn_exp2f(acc * C2);
    if (b == 0) w2n[f] = -2.0f * W2[f];
  } else {
    int id = ((blockIdx.x - BDIM) * 256 + threadIdx.x) * 4;   // 0..65532
    int f = id >> 8, c = id & 255;
    float4 v = *(const float4*)(W1 + (size_t)f * 512 + 256 + c);
    float xs[4] = {v.x, v.y, v.z, v.w};
    #pragma unroll
    for (int e = 0; e < 4; ++e) {
      unsigned short h = f2bf(xs[e]);
      wh[id + e] = h;
      wl[id + e] = f2bf(xs[e] - bf2f(h));
    }
  }
}

// K23: fused k2_mfma + k3_score + out-copy, SOFTWARE-PIPELINED phase 1.
// Phase 1: hm = memory . W1m^T via bf16-split MFMA. Per k-step:
//   barrier -> regs(s)->LDS (+out-store) -> barrier -> ISSUE loads(s+1) ->
//   frag reads + 28 MFMA. Loads for s+1 are in flight across the MFMA and the
//   next barrier (T14 issue-early/write-late), so HBM/L2 latency is hidden
//   instead of serially exposed 8x per block.
// Phase 2: 8 waves x 4 b, lane = m; 4-f partial-fraction grouping, 1 rcp/4f.
__global__ __launch_bounds__(512, 4) void k23_fused(const float* __restrict__ mem,
                                                    const unsigned short* __restrict__ wh,
                                                    const unsigned short* __restrict__ wl,
                                                    const float* __restrict__ Ex,
                                                    const float* __restrict__ w2n,
                                                    float* __restrict__ pmax,
                                                    float* __restrict__ psum,
                                                    int* __restrict__ parg,
                                                    float* __restrict__ out) {
  __shared__ __align__(16) char smem[69632];          // max(51200 staging, 256*68*4 emT)
  unsigned short* AH = (unsigned short*)(smem);        // 64*40  = 5120 B
  unsigned short* AL = (unsigned short*)(smem + 5120);
  unsigned short* BH = (unsigned short*)(smem + 10240);// 256*40 = 20480 B
  unsigned short* BL = (unsigned short*)(smem + 30720);
  float* emT = (float*)smem;                           // phase 2: [256][68] f32

  const int tid = threadIdx.x;
  const int lane = tid & 63, wid = tid >> 6;
  const int m0 = blockIdx.x * 64;
  const int rb = lane & 15, g8 = (lane >> 4) * 8;
  const int mh = wid & 1;        // m-half (32 rows)
  const int fq = wid >> 1;       // f-quarter (64 cols)

  // staging prefetch registers (A-waves: 8 f32; B-waves: 8x uint4)
  float4 pa0, pa1;
  uint4  pb[8];
  const int ar = tid >> 2, ac8 = (tid & 3) * 8;        // A thread geometry
  const int bt2 = tid - 256;                           // B thread geometry

  auto LOADS = [&](int s) {
    const int k0 = s * 32;
    if (tid < 256) {
      const float* mrow = mem + (size_t)(m0 + ar) * 256 + k0 + ac8;
      pa0 = *(const float4*)(mrow);
      pa1 = *(const float4*)(mrow + 4);
    } else {
      #pragma unroll
      for (int q = 0; q < 4; ++q) {
        int id = q * 256 + bt2, br = id >> 2, bc = (id & 3) * 8;
        pb[q * 2 + 0] = *(const uint4*)(wh + (size_t)br * 256 + k0 + bc);
        pb[q * 2 + 1] = *(const uint4*)(wl + (size_t)br * 256 + k0 + bc);
      }
    }
  };

  auto WRITES = [&](int s) {
    const int k0 = s * 32;
    if (tid < 256) {
      float* orow = out + (size_t)(m0 + ar) * 256 + k0 + ac8;
      *(float4*)(orow)     = pa0;            // folded k0_copy (fire-and-forget)
      *(float4*)(orow + 4) = pa1;
      float xs[8] = {pa0.x, pa0.y, pa0.z, pa0.w, pa1.x, pa1.y, pa1.z, pa1.w};
      ushort8 ahv, alv;
      #pragma unroll
      for (int e = 0; e < 8; ++e) {
        unsigned short h = f2bf(xs[e]);
        ahv[e] = h;
        alv[e] = f2bf(xs[e] - bf2f(h));
      }
      *(ushort8*)&AH[ar * 40 + ac8] = ahv;
      *(ushort8*)&AL[ar * 40 + ac8] = alv;
    } else {
      #pragma unroll
      for (int q = 0; q < 4; ++q) {
        int id = q * 256 + bt2, br = id >> 2, bc = (id & 3) * 8;
        *(uint4*)&BH[br * 40 + bc] = pb[q * 2 + 0];
        *(uint4*)&BL[br * 40 + bc] = pb[q * 2 + 1];
      }
    }
  };

  f32x4 acc[2][4];
  #pragma unroll
  for (int i = 0; i < 2; ++i)
    #pragma unroll
    for (int j = 0; j < 4; ++j) acc[i][j] = (f32x4){0.f, 0.f, 0.f, 0.f};

  LOADS(0);                      // prologue
  for (int s = 0; s < 8; ++s) {
    __syncthreads();             // prior frag reads complete; LDS writable
    WRITES(s);
    __syncthreads();
    if (s < 7) LOADS(s + 1);     // in flight across frags+MFMA+next barrier

    bf16x8 fah[2], fal[2], fbh[4], fbl[4];
    #pragma unroll
    for (int i = 0; i < 2; ++i) {
      fah[i] = *(const bf16x8*)&AH[(mh * 32 + i * 16 + rb) * 40 + g8];
      fal[i] = *(const bf16x8*)&AL[(mh * 32 + i * 16 + rb) * 40 + g8];
    }
    #pragma unroll
    for (int j = 0; j < 4; ++j) {
      fbh[j] = *(const bf16x8*)&BH[(fq * 64 + j * 16 + rb) * 40 + g8];
      fbl[j] = *(const bf16x8*)&BL[(fq * 64 + j * 16 + rb) * 40 + g8];
    }
    #pragma unroll
    for (int i = 0; i < 2; ++i)
      #pragma unroll
      for (int j = 0; j < 4; ++j) {
        acc[i][j] = __builtin_amdgcn_mfma_f32_16x16x32_bf16(fah[i], fbh[j], acc[i][j], 0, 0, 0);
        acc[i][j] = __builtin_amdgcn_mfma_f32_16x16x32_bf16(fah[i], fbl[j], acc[i][j], 0, 0, 0);
        acc[i][j] = __builtin_amdgcn_mfma_f32_16x16x32_bf16(fal[i], fbh[j], acc[i][j], 0, 0, 0);
      }
  }

  // Epilogue: em -> LDS (transposed [f][m], pad 68). D frag: f = fq*64+j*16+rb,
  // m_local = mh*32+i*16+(lane>>4)*4 + r (r = reg idx -> one float4 along m).
  __syncthreads();   // all frag reads done before staging buffers are overwritten
  #pragma unroll
  for (int j = 0; j < 4; ++j)
    #pragma unroll
    for (int i = 0; i < 2; ++i) {
      const int fl = fq * 64 + j * 16 + rb;
      const int mloc = mh * 32 + i * 16 + (lane >> 4) * 4;
      float4 v;
      v.x = __builtin_amdgcn_exp2f(acc[i][j][0] * C2);
      v.y = __builtin_amdgcn_exp2f(acc[i][j][1] * C2);
      v.z = __builtin_amdgcn_exp2f(acc[i][j][2] * C2);
      v.w = __builtin_amdgcn_exp2f(acc[i][j][3] * C2);
      *(float4*)(emT + fl * 68 + mloc) = v;
    }
  __syncthreads();

  // Phase 2: score. Wave owns 4 b; lane = local m. 4-f groups share one rcp:
  //   sum_{i=0..3} w_i/u_i = [(w0u1+w1u0)u2u3 + (w2u3+w3u2)u0u1] / (u0u1u2u3)
  const int wuid = __builtin_amdgcn_readfirstlane(wid);  // 0..7
  const float* ex0 = Ex + (size_t)(wuid * 4 + 0) * FDIM;
  const float* ex1 = Ex + (size_t)(wuid * 4 + 1) * FDIM;
  const float* ex2 = Ex + (size_t)(wuid * 4 + 2) * FDIM;
  const float* ex3 = Ex + (size_t)(wuid * 4 + 3) * FDIM;

  float acc0 = 0.f, acc1 = 0.f, acc2 = 0.f, acc3 = 0.f;
  #pragma unroll 2
  for (int f = 0; f < FDIM; f += 4) {
    float e0 = emT[(f + 0) * 68 + lane];
    float e1 = emT[(f + 1) * 68 + lane];
    float e2 = emT[(f + 2) * 68 + lane];
    float e3 = emT[(f + 3) * 68 + lane];
    float w0 = w2n[f + 0], w1 = w2n[f + 1];   // uniform -> SGPR
    float w2 = w2n[f + 2], w3 = w2n[f + 3];
    #define SCORE4(exP, accV)                                            \
    {                                                                    \
      float u0 = fmaf(e0, exP[f + 0], 1.f);                              \
      float u1 = fmaf(e1, exP[f + 1], 1.f);                              \
      float u2 = fmaf(e2, exP[f + 2], 1.f);                              \
      float u3 = fmaf(e3, exP[f + 3], 1.f);                              \
      float p01 = u0 * u1, p23 = u2 * u3;                                \
      float den = p01 * p23;                                             \
      float t0 = fmaf(w1, u0, w0 * u1);                                  \
      float t1 = fmaf(w3, u2, w2 * u3);                                  \
      float num = fmaf(t1, p01, t0 * p23);                               \
      accV = fmaf(num, __builtin_amdgcn_rcpf(den), accV);                \
    }
    SCORE4(ex0, acc0)
    SCORE4(ex1, acc1)
    SCORE4(ex2, acc2)
    SCORE4(ex3, acc3)
    #undef SCORE4
  }

  // wave reduce per owned b: max+argmax over 64 m lanes, then sumexp
  float accb[4] = {acc0, acc1, acc2, acc3};
  const int blk = blockIdx.x;
  #pragma unroll
  for (int bi = 0; bi < 4; ++bi) {
    float s = accb[bi]; int idx = m0 + lane;
    #pragma unroll
    for (int off = 32; off > 0; off >>= 1) {
      float so = __shfl_xor(s, off);
      int   io = __shfl_xor(idx, off);
      if (so > s || (so == s && io < idx)) { s = so; idx = io; }
    }
    float ex = __expf(accb[bi] - s);
    #pragma unroll
    for (int off = 32; off > 0; off >>= 1) ex += __shfl_xor(ex, off);
    if (lane == 0) {
      int b = wuid * 4 + bi;
      pmax[b * NB + blk] = s;
      psum[b * NB + blk] = ex;
      parg[b * NB + blk] = idx;
    }
  }
}

// K4a: per-b parallel merge of NB partials (32 blocks x 256 thr)
__global__ __launch_bounds__(256) void k4a_reduce(const float* __restrict__ pmax,
                                                  const float* __restrict__ psum,
                                                  const int* __restrict__ parg,
                                                  float* __restrict__ gmax,
                                                  float* __restrict__ gsum,
                                                  int* __restrict__ garg) {
  __shared__ float sm[4], ss[4];
  __shared__ int   sa[4];
  const int b = blockIdx.x, tid = threadIdx.x;
  float cm = -3.0e38f, cs = 0.f; int ca = 0x7fffffff;
  #pragma unroll
  for (int t = 0; t < NB / 256; ++t) {
    int i = t * 256 + tid;
    float s = pmax[b * NB + i];
    float p = psum[b * NB + i];
    int   a = parg[b * NB + i];
    if (s > cm)      { cs = cs * __expf(cm - s) + p; cm = s; ca = a; }
    else if (s == cm){ cs += p; if (a < ca) ca = a; }
    else             { cs += p * __expf(s - cm); }
  }
  #pragma unroll
  for (int off = 32; off > 0; off >>= 1) {
    float om = __shfl_xor(cm, off);
    float os = __shfl_xor(cs, off);
    int   oa = __shfl_xor(ca, off);
    if (om > cm)      { cs = cs * __expf(cm - om) + os; cm = om; ca = oa; }
    else if (om == cm){ cs += os; if (oa < ca) ca = oa; }
    else              { cs += os * __expf(om - cm); }
  }
  if ((tid & 63) == 0) { sm[tid >> 6] = cm; ss[tid >> 6] = cs; sa[tid >> 6] = ca; }
  __syncthreads();
  if (tid == 0) {
    cm = sm[0]; cs = ss[0]; ca = sa[0];
    for (int w = 1; w < 4; ++w) {
      float om = sm[w], os = ss[w]; int oa = sa[w];
      if (om > cm)      { cs = cs * __expf(cm - om) + os; cm = om; ca = oa; }
      else if (om == cm){ cs += os; if (oa < ca) ca = oa; }
      else              { cs += os * __expf(om - cm); }
    }
    gmax[b] = cm; gsum[b] = cs; garg[b] = ca;
  }
}

// K5: fused select + patch. 32 blocks; each block redundantly computes its own
// win mask (mask + winner-per-slot dedup, winner = LARGEST masked b per slot),
// then patches out[best[b]] = input[b] if it won. Saves one launch vs k4b+k6.
__global__ __launch_bounds__(64) void k5_select_patch(const float* __restrict__ gsum,
                                                      const int* __restrict__ garg,
                                                      const float* __restrict__ thr_p,
                                                      const float* __restrict__ input,
                                                      float* __restrict__ out) {
  const int b = blockIdx.x;
  const float thr = *thr_p;
  const int me = garg[b];
  int w = (1.0f / gsum[b] > thr) ? 1 : 0;   // maxw = 1/sumexp
  if (w) {
    for (int b2 = b + 1; b2 < BDIM; ++b2)
      if ((1.0f / gsum[b2] > thr) && garg[b2] == me) { w = 0; break; }
  }
  if (!w) return;
  const int t = threadIdx.x;
  *(float4*)(out + (size_t)me * 256 + t * 4) = *(const float4*)(input + (size_t)b * 256 + t * 4);
}

extern "C" void kernel_launch(void* const* d_in, const int* in_sizes, int n_in,
                              void* d_out, int out_size, void* d_ws, size_t ws_size,
                              hipStream_t stream) {
  const float* input  = (const float*)d_in[0];
  const float* memory = (const float*)d_in[1];
  const float* W1     = (const float*)d_in[2];
  const float* b1     = (const float*)d_in[3];
  const float* W2     = (const float*)d_in[4];
  // d_in[5] = b2: constant score shift, softmax/argmax/maxw invariant -> unused
  const float* thr    = (const float*)d_in[6];

  float* ws   = (float*)d_ws;
  float* Ex   = ws + WS_EX;
  float* w2n  = ws + WS_W2N;
  float* pmax = ws + WS_PMAX;
  float* psum = ws + WS_PSUM;
  int*   parg = (int*)(ws + WS_PARG);
  float* gmax = ws + WS_GMAX;
  float* gsum = ws + WS_GSUM;
  int*   garg = (int*)(ws + WS_GARG);
  unsigned short* wh = (unsigned short*)(ws + WS_WH);
  unsigned short* wl = (unsigned short*)(ws + WS_WL);
  float* out  = (float*)d_out;

  hipLaunchKernelGGL(k1_prep,    dim3(BDIM + 64), dim3(256), 0, stream, input, W1, b1, W2, Ex, w2n, wh, wl);
  hipLaunchKernelGGL(k23_fused,  dim3(MDIM / 64), dim3(512), 0, stream, memory, wh, wl, Ex, w2n, pmax, psum, parg, out);
  hipLaunchKernelGGL(k4a_reduce, dim3(BDIM),      dim3(256), 0, stream, pmax, psum, parg, gmax, gsum, garg);
  hipLaunchKernelGGL(k5_select_patch, dim3(BDIM), dim3(64),  0, stream, gsum, garg, thr, input, out);
}

// Round 4
// 75.592 us; speedup vs baseline: 1.1579x; 1.1579x over previous
//
#include <hip/hip_runtime.h>

// Problem constants
#define FDIM 256
#define BDIM 32
#define MDIM 32768
#define NB   512        // m-tiles (64 m each); one partial per (b, tile)

// ws layout (float units)
#define WS_EM    0                       // (unused after fusion; kept for layout stability)
#define WS_EX    (WS_EM + MDIM*FDIM)
#define WS_W2N   (WS_EX + BDIM*FDIM)
#define WS_PMAX  (WS_W2N + FDIM)
#define WS_PSUM  (WS_PMAX + BDIM*NB)
#define WS_PARG  (WS_PSUM + BDIM*NB)
#define WS_WIN   (WS_PARG + BDIM*NB)
#define WS_BEST  (WS_WIN + 32)
#define WS_GMAX  (WS_BEST + 32)
#define WS_GSUM  (WS_GMAX + 32)
#define WS_GARG  (WS_GSUM + 32)
#define WS_WH    (WS_GARG + 32)          // W1m hi: 65536 bf16
#define WS_WL    (WS_WH + 32768)         // W1m lo

#define C2 2.8853900817779268f   // 2*log2(e): e^{2x} = 2^(C2*x)

typedef __attribute__((ext_vector_type(8))) short bf16x8;
typedef __attribute__((ext_vector_type(8))) unsigned short ushort8;
typedef __attribute__((ext_vector_type(4))) float f32x4;

#define AS1 __attribute__((address_space(1)))
#define AS3 __attribute__((address_space(3)))

__device__ __forceinline__ void gload16(const void* g, void* l) {
  // global -> LDS direct DMA, 16 B/lane (LDS dest = uniform base + lane*16)
  __builtin_amdgcn_global_load_lds((const AS1 void*)g, (AS3 void*)l, 16, 0, 0);
}

__device__ inline unsigned short f2bf(float x) {      // RNE f32 -> bf16
  unsigned u = __float_as_uint(x);
  return (unsigned short)((u + 0x7fffu + ((u >> 16) & 1u)) >> 16);
}
__device__ inline float bf2f(unsigned short h) {
  return __uint_as_float(((unsigned)h) << 16);
}

// K1: blocks 0..31: Ex[b][f] = 2^(C2*(b1[f] + sum_k input[b][k]*W1[f*512+k])); w2n = -2*W2
//     blocks 32..95: split W1m into bf16 hi/lo arrays
__global__ __launch_bounds__(256) void k1_prep(const float* __restrict__ input,
                                               const float* __restrict__ W1,
                                               const float* __restrict__ b1,
                                               const float* __restrict__ W2,
                                               float* __restrict__ Ex,
                                               float* __restrict__ w2n,
                                               unsigned short* __restrict__ wh,
                                               unsigned short* __restrict__ wl) {
  if (blockIdx.x < BDIM) {
    const int b = blockIdx.x, f = threadIdx.x;
    const float* in = input + b * FDIM;
    const float* w  = W1 + (size_t)f * 512;
    float acc = b1[f];
    #pragma unroll 8
    for (int k = 0; k < FDIM; k += 4) {
      float4 iv = *(const float4*)(in + k);
      float4 wv = *(const float4*)(w + k);
      acc = fmaf(iv.x, wv.x, acc); acc = fmaf(iv.y, wv.y, acc);
      acc = fmaf(iv.z, wv.z, acc); acc = fmaf(iv.w, wv.w, acc);
    }
    Ex[b * FDIM + f] = __builtin_amdgcn_exp2f(acc * C2);
    if (b == 0) w2n[f] = -2.0f * W2[f];
  } else {
    int id = ((blockIdx.x - BDIM) * 256 + threadIdx.x) * 4;   // 0..65532
    int f = id >> 8, c = id & 255;
    float4 v = *(const float4*)(W1 + (size_t)f * 512 + 256 + c);
    float xs[4] = {v.x, v.y, v.z, v.w};
    #pragma unroll
    for (int e = 0; e < 4; ++e) {
      unsigned short h = f2bf(xs[e]);
      wh[id + e] = h;
      wl[id + e] = f2bf(xs[e] - bf2f(h));
    }
  }
}

// K23: fused k2_mfma + k3_score + out-copy, RAW-BARRIER pipelined phase 1.
// Per k-step: frag-reads -> lgkm0+bar1 -> stage(s+1) [A: ds_write from 1-deep
// reg prefetch + out-store + issue loads(s+2); B: 8x global_load_lds width 16,
// XOR-swizzled SOURCE address, linear LDS] -> MFMA(s) overlaps staging ->
// {A: lgkm0 | B: vmcnt0} + bar2. Counted per-wave waits let A-loads fly ~2
// steps (~900cy HBM hidden); B gload_lds hides under MFMA. No prefetch VGPR
// arrays (R3's pb[8] spilled to scratch: WRITE_SIZE 34->112 MB).
// B LDS layout: unpadded [256][32] bf16; bank-conflict fix via byte-XOR
// bo ^= ((row>>1)&3)<<4 applied on BOTH the gload source addr and frag read.
__global__ __launch_bounds__(512, 4) void k23_fused(const float* __restrict__ mem,
                                                    const unsigned short* __restrict__ wh,
                                                    const unsigned short* __restrict__ wl,
                                                    const float* __restrict__ Ex,
                                                    const float* __restrict__ w2n,
                                                    float* __restrict__ pmax,
                                                    float* __restrict__ psum,
                                                    int* __restrict__ parg,
                                                    float* __restrict__ out) {
  __shared__ __align__(16) char smem[69632];   // staging 43008 B; emT 69632 B (aliased)
  unsigned short* AH = (unsigned short*)(smem);          // 64*40*2  = 5120 B (padded)
  unsigned short* AL = (unsigned short*)(smem + 5120);
  char* BHb = smem + 10240;                              // 256*32*2 = 16384 B (linear)
  char* BLb = smem + 26624;                              // 16384 B
  float* emT = (float*)smem;                             // phase 2: [256][68] f32

  const int tid = threadIdx.x;
  const int lane = tid & 63, wid = tid >> 6;
  const int m0 = blockIdx.x * 64;
  const int rb = lane & 15, g8 = (lane >> 4) * 8;
  const int mh = wid & 1;        // m-half (32 rows)
  const int fq = wid >> 1;       // f-quarter (64 cols)

  const int ar = tid >> 2, ac8 = (tid & 3) * 8;          // A staging geometry
  const int iw = wid - 4;                                // B wave 0..3
  const int brow_l = lane >> 2, bbo = (lane & 3) * 16;   // B lane geometry

  float4 pa0, pa1;   // 1-deep A prefetch (8 VGPR)

  // ---- prologue: stage k-step 0, prefetch A(1) ----
  if (tid < 256) {
    const float* mrow = mem + (size_t)(m0 + ar) * 256 + ac8;
    float4 a0 = *(const float4*)(mrow);
    float4 a1 = *(const float4*)(mrow + 4);
    float* orow = out + (size_t)(m0 + ar) * 256 + ac8;
    *(float4*)(orow)     = a0;
    *(float4*)(orow + 4) = a1;
    float xs[8] = {a0.x, a0.y, a0.z, a0.w, a1.x, a1.y, a1.z, a1.w};
    ushort8 ahv, alv;
    #pragma unroll
    for (int e = 0; e < 8; ++e) {
      unsigned short h = f2bf(xs[e]);
      ahv[e] = h;
      alv[e] = f2bf(xs[e] - bf2f(h));
    }
    *(ushort8*)&AH[ar * 40 + ac8] = ahv;
    *(ushort8*)&AL[ar * 40 + ac8] = alv;
    const float* mrow1 = mem + (size_t)(m0 + ar) * 256 + 32 + ac8;
    pa0 = *(const float4*)(mrow1);
    pa1 = *(const float4*)(mrow1 + 4);
  } else {
    #pragma unroll
    for (int q = 0; q < 4; ++q) {
      const int c = iw * 4 + q;
      const int row = c * 16 + brow_l;
      const int sbo = bbo ^ (((row >> 1) & 3) << 4);
      gload16(wh + (size_t)row * 256 + (sbo >> 1), BHb + c * 1024);
      gload16(wl + (size_t)row * 256 + (sbo >> 1), BLb + c * 1024);
    }
    asm volatile("s_waitcnt vmcnt(0)" ::: "memory");
  }
  __syncthreads();

  f32x4 acc[2][4];
  #pragma unroll
  for (int i = 0; i < 2; ++i)
    #pragma unroll
    for (int j = 0; j < 4; ++j) acc[i][j] = (f32x4){0.f, 0.f, 0.f, 0.f};

  for (int s = 0; s < 8; ++s) {
    // frag reads from current (single-buffered) tiles
    bf16x8 fah[2], fal[2], fbh[4], fbl[4];
    #pragma unroll
    for (int i = 0; i < 2; ++i) {
      fah[i] = *(const bf16x8*)&AH[(mh * 32 + i * 16 + rb) * 40 + g8];
      fal[i] = *(const bf16x8*)&AL[(mh * 32 + i * 16 + rb) * 40 + g8];
    }
    #pragma unroll
    for (int j = 0; j < 4; ++j) {
      const int row = fq * 64 + j * 16 + rb;
      const int bo  = (g8 * 2) ^ (((row >> 1) & 3) << 4);
      fbh[j] = *(const bf16x8*)(BHb + row * 64 + bo);
      fbl[j] = *(const bf16x8*)(BLb + row * 64 + bo);
    }
    asm volatile("s_waitcnt lgkmcnt(0)" ::: "memory");   // reads retired
    __builtin_amdgcn_sched_barrier(0);
    __builtin_amdgcn_s_barrier();                        // bar1: tiles reusable
    __builtin_amdgcn_sched_barrier(0);

    if (s < 7) {
      const int k1o = (s + 1) * 32;
      if (tid < 256) {
        float xs[8] = {pa0.x, pa0.y, pa0.z, pa0.w, pa1.x, pa1.y, pa1.z, pa1.w};
        ushort8 ahv, alv;
        #pragma unroll
        for (int e = 0; e < 8; ++e) {
          unsigned short h = f2bf(xs[e]);
          ahv[e] = h;
          alv[e] = f2bf(xs[e] - bf2f(h));
        }
        *(ushort8*)&AH[ar * 40 + ac8] = ahv;
        *(ushort8*)&AL[ar * 40 + ac8] = alv;
        float* orow = out + (size_t)(m0 + ar) * 256 + k1o + ac8;
        *(float4*)(orow)     = pa0;          // folded k0_copy
        *(float4*)(orow + 4) = pa1;
        if (s < 6) {                         // prefetch A(s+2): flies 2 steps
          const float* mrow = mem + (size_t)(m0 + ar) * 256 + k1o + 32 + ac8;
          pa0 = *(const float4*)(mrow);
          pa1 = *(const float4*)(mrow + 4);
        }
      } else {
        #pragma unroll
        for (int q = 0; q < 4; ++q) {
          const int c = iw * 4 + q;
          const int row = c * 16 + brow_l;
          const int sbo = bbo ^ (((row >> 1) & 3) << 4);
          gload16(wh + (size_t)row * 256 + k1o + (sbo >> 1), BHb + c * 1024);
          gload16(wl + (size_t)row * 256 + k1o + (sbo >> 1), BLb + c * 1024);
        }
      }
    }

    // MFMA(s): register-only; compiler interleaves with staging issue above
    #pragma unroll
    for (int i = 0; i < 2; ++i)
      #pragma unroll
      for (int j = 0; j < 4; ++j) {
        acc[i][j] = __builtin_amdgcn_mfma_f32_16x16x32_bf16(fah[i], fbh[j], acc[i][j], 0, 0, 0);
        acc[i][j] = __builtin_amdgcn_mfma_f32_16x16x32_bf16(fah[i], fbl[j], acc[i][j], 0, 0, 0);
        acc[i][j] = __builtin_amdgcn_mfma_f32_16x16x32_bf16(fal[i], fbh[j], acc[i][j], 0, 0, 0);
      }

    if (s < 7) {
      if (tid < 256) {   // wave-uniform branch
        asm volatile("s_waitcnt lgkmcnt(0)" ::: "memory");  // A ds_writes visible
      } else {
        asm volatile("s_waitcnt vmcnt(0)" ::: "memory");    // gload_lds landed
      }
      __builtin_amdgcn_sched_barrier(0);
      __builtin_amdgcn_s_barrier();                         // bar2: next tile ready
      __builtin_amdgcn_sched_barrier(0);
    }
  }

  // Epilogue: em -> LDS (transposed [f][m], pad 68). D frag: f = fq*64+j*16+rb,
  // m_local = mh*32+i*16+(lane>>4)*4 + r (r = reg idx -> one float4 along m).
  __syncthreads();   // full drain once: frag reads done before emT overwrites staging
  #pragma unroll
  for (int j = 0; j < 4; ++j)
    #pragma unroll
    for (int i = 0; i < 2; ++i) {
      const int fl = fq * 64 + j * 16 + rb;
      const int mloc = mh * 32 + i * 16 + (lane >> 4) * 4;
      float4 v;
      v.x = __builtin_amdgcn_exp2f(acc[i][j][0] * C2);
      v.y = __builtin_amdgcn_exp2f(acc[i][j][1] * C2);
      v.z = __builtin_amdgcn_exp2f(acc[i][j][2] * C2);
      v.w = __builtin_amdgcn_exp2f(acc[i][j][3] * C2);
      *(float4*)(emT + fl * 68 + mloc) = v;
    }
  __syncthreads();

  // Phase 2: score. Wave owns 4 b; lane = local m. 4-f groups share one rcp:
  //   sum_{i=0..3} w_i/u_i = [(w0u1+w1u0)u2u3 + (w2u3+w3u2)u0u1] / (u0u1u2u3)
  const int wuid = __builtin_amdgcn_readfirstlane(wid);  // 0..7
  const float* ex0 = Ex + (size_t)(wuid * 4 + 0) * FDIM;
  const float* ex1 = Ex + (size_t)(wuid * 4 + 1) * FDIM;
  const float* ex2 = Ex + (size_t)(wuid * 4 + 2) * FDIM;
  const float* ex3 = Ex + (size_t)(wuid * 4 + 3) * FDIM;

  float acc0 = 0.f, acc1 = 0.f, acc2 = 0.f, acc3 = 0.f;
  #pragma unroll 2
  for (int f = 0; f < FDIM; f += 4) {
    float e0 = emT[(f + 0) * 68 + lane];
    float e1 = emT[(f + 1) * 68 + lane];
    float e2 = emT[(f + 2) * 68 + lane];
    float e3 = emT[(f + 3) * 68 + lane];
    float w0 = w2n[f + 0], w1 = w2n[f + 1];   // uniform -> SGPR
    float w2 = w2n[f + 2], w3 = w2n[f + 3];
    #define SCORE4(exP, accV)                                            \
    {                                                                    \
      float u0 = fmaf(e0, exP[f + 0], 1.f);                              \
      float u1 = fmaf(e1, exP[f + 1], 1.f);                              \
      float u2 = fmaf(e2, exP[f + 2], 1.f);                              \
      float u3 = fmaf(e3, exP[f + 3], 1.f);                              \
      float p01 = u0 * u1, p23 = u2 * u3;                                \
      float den = p01 * p23;                                             \
      float t0 = fmaf(w1, u0, w0 * u1);                                  \
      float t1 = fmaf(w3, u2, w2 * u3);                                  \
      float num = fmaf(t1, p01, t0 * p23);                               \
      accV = fmaf(num, __builtin_amdgcn_rcpf(den), accV);                \
    }
    SCORE4(ex0, acc0)
    SCORE4(ex1, acc1)
    SCORE4(ex2, acc2)
    SCORE4(ex3, acc3)
    #undef SCORE4
  }

  // wave reduce per owned b: max+argmax over 64 m lanes, then sumexp
  float accb[4] = {acc0, acc1, acc2, acc3};
  const int blk = blockIdx.x;
  #pragma unroll
  for (int bi = 0; bi < 4; ++bi) {
    float s = accb[bi]; int idx = m0 + lane;
    #pragma unroll
    for (int off = 32; off > 0; off >>= 1) {
      float so = __shfl_xor(s, off);
      int   io = __shfl_xor(idx, off);
      if (so > s || (so == s && io < idx)) { s = so; idx = io; }
    }
    float ex = __expf(accb[bi] - s);
    #pragma unroll
    for (int off = 32; off > 0; off >>= 1) ex += __shfl_xor(ex, off);
    if (lane == 0) {
      int b = wuid * 4 + bi;
      pmax[b * NB + blk] = s;
      psum[b * NB + blk] = ex;
      parg[b * NB + blk] = idx;
    }
  }
}

// K4a: per-b parallel merge of NB partials (32 blocks x 256 thr)
__global__ __launch_bounds__(256) void k4a_reduce(const float* __restrict__ pmax,
                                                  const float* __restrict__ psum,
                                                  const int* __restrict__ parg,
                                                  float* __restrict__ gmax,
                                                  float* __restrict__ gsum,
                                                  int* __restrict__ garg) {
  __shared__ float sm[4], ss[4];
  __shared__ int   sa[4];
  const int b = blockIdx.x, tid = threadIdx.x;
  float cm = -3.0e38f, cs = 0.f; int ca = 0x7fffffff;
  #pragma unroll
  for (int t = 0; t < NB / 256; ++t) {
    int i = t * 256 + tid;
    float s = pmax[b * NB + i];
    float p = psum[b * NB + i];
    int   a = parg[b * NB + i];
    if (s > cm)      { cs = cs * __expf(cm - s) + p; cm = s; ca = a; }
    else if (s == cm){ cs += p; if (a < ca) ca = a; }
    else             { cs += p * __expf(s - cm); }
  }
  #pragma unroll
  for (int off = 32; off > 0; off >>= 1) {
    float om = __shfl_xor(cm, off);
    float os = __shfl_xor(cs, off);
    int   oa = __shfl_xor(ca, off);
    if (om > cm)      { cs = cs * __expf(cm - om) + os; cm = om; ca = oa; }
    else if (om == cm){ cs += os; if (oa < ca) ca = oa; }
    else              { cs += os * __expf(om - cm); }
  }
  if ((tid & 63) == 0) { sm[tid >> 6] = cm; ss[tid >> 6] = cs; sa[tid >> 6] = ca; }
  __syncthreads();
  if (tid == 0) {
    cm = sm[0]; cs = ss[0]; ca = sa[0];
    for (int w = 1; w < 4; ++w) {
      float om = sm[w], os = ss[w]; int oa = sa[w];
      if (om > cm)      { cs = cs * __expf(cm - om) + os; cm = om; ca = oa; }
      else if (om == cm){ cs += os; if (oa < ca) ca = oa; }
      else              { cs += os * __expf(om - cm); }
    }
    gmax[b] = cm; gsum[b] = cs; garg[b] = ca;
  }
}

// K5: fused select + patch. 32 blocks; each block redundantly computes its own
// win mask (mask + winner-per-slot dedup, winner = LARGEST masked b per slot),
// then patches out[best[b]] = input[b] if it won.
__global__ __launch_bounds__(64) void k5_select_patch(const float* __restrict__ gsum,
                                                      const int* __restrict__ garg,
                                                      const float* __restrict__ thr_p,
                                                      const float* __restrict__ input,
                                                      float* __restrict__ out) {
  const int b = blockIdx.x;
  const float thr = *thr_p;
  const int me = garg[b];
  int w = (1.0f / gsum[b] > thr) ? 1 : 0;   // maxw = 1/sumexp
  if (w) {
    for (int b2 = b + 1; b2 < BDIM; ++b2)
      if ((1.0f / gsum[b2] > thr) && garg[b2] == me) { w = 0; break; }
  }
  if (!w) return;
  const int t = threadIdx.x;
  *(float4*)(out + (size_t)me * 256 + t * 4) = *(const float4*)(input + (size_t)b * 256 + t * 4);
}

extern "C" void kernel_launch(void* const* d_in, const int* in_sizes, int n_in,
                              void* d_out, int out_size, void* d_ws, size_t ws_size,
                              hipStream_t stream) {
  const float* input  = (const float*)d_in[0];
  const float* memory = (const float*)d_in[1];
  const float* W1     = (const float*)d_in[2];
  const float* b1     = (const float*)d_in[3];
  const float* W2     = (const float*)d_in[4];
  // d_in[5] = b2: constant score shift, softmax/argmax/maxw invariant -> unused
  const float* thr    = (const float*)d_in[6];

  float* ws   = (float*)d_ws;
  float* Ex   = ws + WS_EX;
  float* w2n  = ws + WS_W2N;
  float* pmax = ws + WS_PMAX;
  float* psum = ws + WS_PSUM;
  int*   parg = (int*)(ws + WS_PARG);
  float* gmax = ws + WS_GMAX;
  float* gsum = ws + WS_GSUM;
  int*   garg = (int*)(ws + WS_GARG);
  unsigned short* wh = (unsigned short*)(ws + WS_WH);
  unsigned short* wl = (unsigned short*)(ws + WS_WL);
  float* out  = (float*)d_out;

  hipLaunchKernelGGL(k1_prep,    dim3(BDIM + 64), dim3(256), 0, stream, input, W1, b1, W2, Ex, w2n, wh, wl);
  hipLaunchKernelGGL(k23_fused,  dim3(MDIM / 64), dim3(512), 0, stream, memory, wh, wl, Ex, w2n, pmax, psum, parg, out);
  hipLaunchKernelGGL(k4a_reduce, dim3(BDIM),      dim3(256), 0, stream, pmax, psum, parg, gmax, gsum, garg);
  hipLaunchKernelGGL(k5_select_patch, dim3(BDIM), dim3(64),  0, stream, gsum, garg, thr, input, out);
}

// Round 5
// 74.149 us; speedup vs baseline: 1.1805x; 1.0195x over previous
//
#include <hip/hip_runtime.h>

// Problem constants
#define FDIM 256
#define BDIM 32
#define MDIM 32768
#define NB   512        // m-tiles (64 m each); one partial per (b, tile)

// ws layout (float units)
#define WS_EM    0                       // (unused after fusion; kept for layout stability)
#define WS_EX    (WS_EM + MDIM*FDIM)
#define WS_W2N   (WS_EX + BDIM*FDIM)
#define WS_PMAX  (WS_W2N + FDIM)
#define WS_PSUM  (WS_PMAX + BDIM*NB)
#define WS_PARG  (WS_PSUM + BDIM*NB)
#define WS_WIN   (WS_PARG + BDIM*NB)
#define WS_BEST  (WS_WIN + 32)
#define WS_GMAX  (WS_BEST + 32)
#define WS_GSUM  (WS_GMAX + 32)
#define WS_GARG  (WS_GSUM + 32)
#define WS_WH    (WS_GARG + 32)          // W1m hi: 65536 bf16
#define WS_WL    (WS_WH + 32768)         // W1m lo

#define C2 2.8853900817779268f   // 2*log2(e): e^{2x} = 2^(C2*x)

typedef __attribute__((ext_vector_type(8))) short bf16x8;
typedef __attribute__((ext_vector_type(8))) unsigned short ushort8;
typedef __attribute__((ext_vector_type(4))) float f32x4;

__device__ inline unsigned short f2bf(float x) {      // RNE f32 -> bf16
  unsigned u = __float_as_uint(x);
  return (unsigned short)((u + 0x7fffu + ((u >> 16) & 1u)) >> 16);
}
__device__ inline float bf2f(unsigned short h) {
  return __uint_as_float(((unsigned)h) << 16);
}

// K1: blocks 0..31: Ex[b][f] = 2^(C2*(b1[f] + sum_k input[b][k]*W1[f*512+k])); w2n = -2*W2
//     blocks 32..95: split W1m into bf16 hi/lo arrays
__global__ __launch_bounds__(256) void k1_prep(const float* __restrict__ input,
                                               const float* __restrict__ W1,
                                               const float* __restrict__ b1,
                                               const float* __restrict__ W2,
                                               float* __restrict__ Ex,
                                               float* __restrict__ w2n,
                                               unsigned short* __restrict__ wh,
                                               unsigned short* __restrict__ wl) {
  if (blockIdx.x < BDIM) {
    const int b = blockIdx.x, f = threadIdx.x;
    const float* in = input + b * FDIM;
    const float* w  = W1 + (size_t)f * 512;
    float acc = b1[f];
    #pragma unroll 8
    for (int k = 0; k < FDIM; k += 4) {
      float4 iv = *(const float4*)(in + k);
      float4 wv = *(const float4*)(w + k);
      acc = fmaf(iv.x, wv.x, acc); acc = fmaf(iv.y, wv.y, acc);
      acc = fmaf(iv.z, wv.z, acc); acc = fmaf(iv.w, wv.w, acc);
    }
    Ex[b * FDIM + f] = __builtin_amdgcn_exp2f(acc * C2);
    if (b == 0) w2n[f] = -2.0f * W2[f];
  } else {
    int id = ((blockIdx.x - BDIM) * 256 + threadIdx.x) * 4;   // 0..65532
    int f = id >> 8, c = id & 255;
    float4 v = *(const float4*)(W1 + (size_t)f * 512 + 256 + c);
    float xs[4] = {v.x, v.y, v.z, v.w};
    #pragma unroll
    for (int e = 0; e < 4; ++e) {
      unsigned short h = f2bf(xs[e]);
      wh[id + e] = h;
      wl[id + e] = f2bf(xs[e] - bf2f(h));
    }
  }
}

// K23: fused k2_mfma + k3_score + out-copy. R2 structure (plain __syncthreads,
// no reg-prefetch pipelining: R3/R4 both spilled — WRITE_SIZE tripwire).
// LDS cut 69632 -> 51200 by running epilogue+score in TWO f-halves:
// emT is [128][68] per pass (34816 B) aliased over the 51200 B staging, so
// occupancy rises from 2 blocks/CU (16 waves) to 3 blocks/CU (20 waves
// after the ~96-unified-reg cap) — +25% TLP against the latency stall.
__global__ __launch_bounds__(512, 4) void k23_fused(const float* __restrict__ mem,
                                                    const unsigned short* __restrict__ wh,
                                                    const unsigned short* __restrict__ wl,
                                                    const float* __restrict__ Ex,
                                                    const float* __restrict__ w2n,
                                                    float* __restrict__ pmax,
                                                    float* __restrict__ psum,
                                                    int* __restrict__ parg,
                                                    float* __restrict__ out) {
  __shared__ __align__(16) char smem[51200];           // staging 51200; emT 34816 (aliased)
  unsigned short* AH = (unsigned short*)(smem);        // 64*40  = 5120 B
  unsigned short* AL = (unsigned short*)(smem + 5120);
  unsigned short* BH = (unsigned short*)(smem + 10240);// 256*40 = 20480 B
  unsigned short* BL = (unsigned short*)(smem + 30720);
  float* emT = (float*)smem;                           // per pass: [128][68] f32

  const int tid = threadIdx.x;
  const int lane = tid & 63, wid = tid >> 6;
  const int m0 = blockIdx.x * 64;
  const int rb = lane & 15, g8 = (lane >> 4) * 8;
  const int mh = wid & 1;        // m-half (32 rows)
  const int fq = wid >> 1;       // f-quarter (64 cols)

  f32x4 acc[2][4];
  #pragma unroll
  for (int i = 0; i < 2; ++i)
    #pragma unroll
    for (int j = 0; j < 4; ++j) acc[i][j] = (f32x4){0.f, 0.f, 0.f, 0.f};

  for (int s = 0; s < 8; ++s) {
    const int k0 = s * 32;
    __syncthreads();   // prior frag reads complete; LDS writable
    if (tid < 256) {   // stage A: 64 rows x 32 k, split to hi/lo; store out=mem
      int r = tid >> 2, c8 = (tid & 3) * 8;
      const float* mrow = mem + (size_t)(m0 + r) * 256 + k0 + c8;
      float4 a0 = *(const float4*)(mrow);
      float4 a1 = *(const float4*)(mrow + 4);
      float* orow = out + (size_t)(m0 + r) * 256 + k0 + c8;
      *(float4*)(orow)     = a0;             // folded k0_copy (fire-and-forget)
      *(float4*)(orow + 4) = a1;
      float xs[8] = {a0.x, a0.y, a0.z, a0.w, a1.x, a1.y, a1.z, a1.w};
      ushort8 ahv, alv;
      #pragma unroll
      for (int e = 0; e < 8; ++e) {
        unsigned short h = f2bf(xs[e]);
        ahv[e] = h;
        alv[e] = f2bf(xs[e] - bf2f(h));
      }
      *(ushort8*)&AH[r * 40 + c8] = ahv;
      *(ushort8*)&AL[r * 40 + c8] = alv;
    } else {           // stage B: 256 rows x 32 k (pre-split, L2-resident)
      int t2 = tid - 256;
      #pragma unroll
      for (int q = 0; q < 4; ++q) {
        int id = q * 256 + t2, br = id >> 2, bc = (id & 3) * 8;
        *(uint4*)&BH[br * 40 + bc] = *(const uint4*)(wh + (size_t)br * 256 + k0 + bc);
        *(uint4*)&BL[br * 40 + bc] = *(const uint4*)(wl + (size_t)br * 256 + k0 + bc);
      }
    }
    __syncthreads();

    bf16x8 fah[2], fal[2], fbh[4], fbl[4];
    #pragma unroll
    for (int i = 0; i < 2; ++i) {
      fah[i] = *(const bf16x8*)&AH[(mh * 32 + i * 16 + rb) * 40 + g8];
      fal[i] = *(const bf16x8*)&AL[(mh * 32 + i * 16 + rb) * 40 + g8];
    }
    #pragma unroll
    for (int j = 0; j < 4; ++j) {
      fbh[j] = *(const bf16x8*)&BH[(fq * 64 + j * 16 + rb) * 40 + g8];
      fbl[j] = *(const bf16x8*)&BL[(fq * 64 + j * 16 + rb) * 40 + g8];
    }
    #pragma unroll
    for (int i = 0; i < 2; ++i)
      #pragma unroll
      for (int j = 0; j < 4; ++j) {
        acc[i][j] = __builtin_amdgcn_mfma_f32_16x16x32_bf16(fah[i], fbh[j], acc[i][j], 0, 0, 0);
        acc[i][j] = __builtin_amdgcn_mfma_f32_16x16x32_bf16(fah[i], fbl[j], acc[i][j], 0, 0, 0);
        acc[i][j] = __builtin_amdgcn_mfma_f32_16x16x32_bf16(fal[i], fbh[j], acc[i][j], 0, 0, 0);
      }
  }

  // Epilogue + phase 2, in TWO f-halves. Pass h: waves with fq in {2h,2h+1}
  // (i.e. wid>>2 == h) write their 128-f slab of em into emT[128][68]; then
  // ALL waves score f in [128h, 128h+128), accumulating acc0..3 across passes.
  // D frag: f = fq*64 + j*16 + rb; m_local = mh*32 + i*16 + (lane>>4)*4 + r.
  const int wuid = __builtin_amdgcn_readfirstlane(wid);  // 0..7
  const float* ex0 = Ex + (size_t)(wuid * 4 + 0) * FDIM;
  const float* ex1 = Ex + (size_t)(wuid * 4 + 1) * FDIM;
  const float* ex2 = Ex + (size_t)(wuid * 4 + 2) * FDIM;
  const float* ex3 = Ex + (size_t)(wuid * 4 + 3) * FDIM;
  float acc0 = 0.f, acc1 = 0.f, acc2 = 0.f, acc3 = 0.f;

  #pragma unroll
  for (int h = 0; h < 2; ++h) {
    __syncthreads();   // h=0: all frag reads done; h=1: pass-0 emT reads done
    if ((wid >> 2) == h) {
      #pragma unroll
      for (int j = 0; j < 4; ++j)
        #pragma unroll
        for (int i = 0; i < 2; ++i) {
          const int fl = (fq * 64 + j * 16 + rb) - h * 128;   // 0..127 local
          const int mloc = mh * 32 + i * 16 + (lane >> 4) * 4;
          float4 v;
          v.x = __builtin_amdgcn_exp2f(acc[i][j][0] * C2);
          v.y = __builtin_amdgcn_exp2f(acc[i][j][1] * C2);
          v.z = __builtin_amdgcn_exp2f(acc[i][j][2] * C2);
          v.w = __builtin_amdgcn_exp2f(acc[i][j][3] * C2);
          *(float4*)(emT + fl * 68 + mloc) = v;
        }
    }
    __syncthreads();

    // score this 128-f slab: 4-f groups share one rcp:
    //   sum_i w_i/u_i = [(w0u1+w1u0)u2u3 + (w2u3+w3u2)u0u1] / (u0u1u2u3)
    #pragma unroll 2
    for (int fl2 = 0; fl2 < 128; fl2 += 4) {
      const int fg = h * 128 + fl2;
      float e0 = emT[(fl2 + 0) * 68 + lane];
      float e1 = emT[(fl2 + 1) * 68 + lane];
      float e2 = emT[(fl2 + 2) * 68 + lane];
      float e3 = emT[(fl2 + 3) * 68 + lane];
      float w0 = w2n[fg + 0], w1 = w2n[fg + 1];   // uniform -> SGPR
      float w2 = w2n[fg + 2], w3 = w2n[fg + 3];
      #define SCORE4(exP, accV)                                          \
      {                                                                  \
        float u0 = fmaf(e0, exP[fg + 0], 1.f);                           \
        float u1 = fmaf(e1, exP[fg + 1], 1.f);                           \
        float u2 = fmaf(e2, exP[fg + 2], 1.f);                           \
        float u3 = fmaf(e3, exP[fg + 3], 1.f);                           \
        float p01 = u0 * u1, p23 = u2 * u3;                              \
        float den = p01 * p23;                                           \
        float t0 = fmaf(w1, u0, w0 * u1);                                \
        float t1 = fmaf(w3, u2, w2 * u3);                                \
        float num = fmaf(t1, p01, t0 * p23);                             \
        accV = fmaf(num, __builtin_amdgcn_rcpf(den), accV);              \
      }
      SCORE4(ex0, acc0)
      SCORE4(ex1, acc1)
      SCORE4(ex2, acc2)
      SCORE4(ex3, acc3)
      #undef SCORE4
    }
  }

  // wave reduce per owned b: max+argmax over 64 m lanes, then sumexp
  float accb[4] = {acc0, acc1, acc2, acc3};
  const int blk = blockIdx.x;
  #pragma unroll
  for (int bi = 0; bi < 4; ++bi) {
    float s = accb[bi]; int idx = m0 + lane;
    #pragma unroll
    for (int off = 32; off > 0; off >>= 1) {
      float so = __shfl_xor(s, off);
      int   io = __shfl_xor(idx, off);
      if (so > s || (so == s && io < idx)) { s = so; idx = io; }
    }
    float ex = __expf(accb[bi] - s);
    #pragma unroll
    for (int off = 32; off > 0; off >>= 1) ex += __shfl_xor(ex, off);
    if (lane == 0) {
      int b = wuid * 4 + bi;
      pmax[b * NB + blk] = s;
      psum[b * NB + blk] = ex;
      parg[b * NB + blk] = idx;
    }
  }
}

// K45: fused reduce + select + patch (single block, 16 waves).
// Wave w merges the 512 partials for b = 2w and 2w+1 (8 per lane + shfl
// tree), results in LDS; then dedup (winner = LARGEST masked b per slot);
// then patch winning rows out[ga[b]] = input[b] (32 threads per b).
__global__ __launch_bounds__(1024) void k45_finish(const float* __restrict__ pmax,
                                                   const float* __restrict__ psum,
                                                   const int* __restrict__ parg,
                                                   const float* __restrict__ thr_p,
                                                   const float* __restrict__ input,
                                                   float* __restrict__ out) {
  __shared__ float gm[BDIM], gs[BDIM];
  __shared__ int   ga[BDIM], wn[BDIM];
  const int tid = threadIdx.x, lane = tid & 63, w = tid >> 6;   // 16 waves
  #pragma unroll
  for (int half = 0; half < 2; ++half) {
    const int b = w * 2 + half;
    float cm = -3.0e38f, cs = 0.f; int ca = 0x7fffffff;
    #pragma unroll
    for (int t = 0; t < NB / 64; ++t) {
      int i = t * 64 + lane;
      float s = pmax[b * NB + i];
      float p = psum[b * NB + i];
      int   a = parg[b * NB + i];
      if (s > cm)      { cs = cs * __expf(cm - s) + p; cm = s; ca = a; }
      else if (s == cm){ cs += p; if (a < ca) ca = a; }
      else             { cs += p * __expf(s - cm); }
    }
    #pragma unroll
    for (int off = 32; off > 0; off >>= 1) {
      float om = __shfl_xor(cm, off);
      float os = __shfl_xor(cs, off);
      int   oa = __shfl_xor(ca, off);
      if (om > cm)      { cs = cs * __expf(cm - om) + os; cm = om; ca = oa; }
      else if (om == cm){ cs += os; if (oa < ca) ca = oa; }
      else              { cs += os * __expf(om - cm); }
    }
    if (lane == 0) { gm[b] = cm; gs[b] = cs; ga[b] = ca; }
  }
  __syncthreads();
  if (tid < BDIM) {
    const float thr = *thr_p;
    const int me = ga[tid];
    int w_ = (1.0f / gs[tid] > thr) ? 1 : 0;   // maxw = 1/sumexp
    if (w_) {
      for (int b2 = tid + 1; b2 < BDIM; ++b2)
        if ((1.0f / gs[b2] > thr) && ga[b2] == me) { w_ = 0; break; }
    }
    wn[tid] = w_;
  }
  __syncthreads();
  {
    const int b = tid >> 5, sub = tid & 31;
    if (wn[b]) {
      const int m = ga[b];
      *(float4*)(out + (size_t)m * 256 + sub * 8) =
          *(const float4*)(input + (size_t)b * 256 + sub * 8);
      *(float4*)(out + (size_t)m * 256 + sub * 8 + 4) =
          *(const float4*)(input + (size_t)b * 256 + sub * 8 + 4);
    }
  }
}

extern "C" void kernel_launch(void* const* d_in, const int* in_sizes, int n_in,
                              void* d_out, int out_size, void* d_ws, size_t ws_size,
                              hipStream_t stream) {
  const float* input  = (const float*)d_in[0];
  const float* memory = (const float*)d_in[1];
  const float* W1     = (const float*)d_in[2];
  const float* b1     = (const float*)d_in[3];
  const float* W2     = (const float*)d_in[4];
  // d_in[5] = b2: constant score shift, softmax/argmax/maxw invariant -> unused
  const float* thr    = (const float*)d_in[6];

  float* ws   = (float*)d_ws;
  float* Ex   = ws + WS_EX;
  float* w2n  = ws + WS_W2N;
  float* pmax = ws + WS_PMAX;
  float* psum = ws + WS_PSUM;
  int*   parg = (int*)(ws + WS_PARG);
  unsigned short* wh = (unsigned short*)(ws + WS_WH);
  unsigned short* wl = (unsigned short*)(ws + WS_WL);
  float* out  = (float*)d_out;

  hipLaunchKernelGGL(k1_prep,    dim3(BDIM + 64), dim3(256),  0, stream, input, W1, b1, W2, Ex, w2n, wh, wl);
  hipLaunchKernelGGL(k23_fused,  dim3(MDIM / 64), dim3(512),  0, stream, memory, wh, wl, Ex, w2n, pmax, psum, parg, out);
  hipLaunchKernelGGL(k45_finish, dim3(1),         dim3(1024), 0, stream, pmax, psum, parg, thr, input, out);
}

// Round 6
// 72.853 us; speedup vs baseline: 1.2015x; 1.0178x over previous
//
#include <hip/hip_runtime.h>

// Problem constants
#define FDIM 256
#define BDIM 32
#define MDIM 32768
#define NB   512        // m-tiles (64 m each); one partial per (b, tile)

// ws layout (float units)
#define WS_EM    0                       // (unused after fusion; kept for layout stability)
#define WS_EX    (WS_EM + MDIM*FDIM)
#define WS_W2N   (WS_EX + BDIM*FDIM)
#define WS_PMAX  (WS_W2N + FDIM)
#define WS_PSUM  (WS_PMAX + BDIM*NB)
#define WS_PARG  (WS_PSUM + BDIM*NB)
#define WS_WIN   (WS_PARG + BDIM*NB)
#define WS_BEST  (WS_WIN + 32)
#define WS_GMAX  (WS_BEST + 32)
#define WS_GSUM  (WS_GMAX + 32)
#define WS_GARG  (WS_GSUM + 32)
#define WS_WH    (WS_GARG + 32)          // W1m hi: 65536 bf16
#define WS_WL    (WS_WH + 32768)         // W1m lo

#define C2 2.8853900817779268f   // 2*log2(e): e^{2x} = 2^(C2*x)

typedef __attribute__((ext_vector_type(8))) short bf16x8;
typedef __attribute__((ext_vector_type(8))) unsigned short ushort8;
typedef __attribute__((ext_vector_type(4))) unsigned short ushort4v;
typedef __attribute__((ext_vector_type(4))) float f32x4;

__device__ inline unsigned short f2bf(float x) {      // RNE f32 -> bf16
  unsigned u = __float_as_uint(x);
  return (unsigned short)((u + 0x7fffu + ((u >> 16) & 1u)) >> 16);
}
__device__ inline float bf2f(unsigned short h) {
  return __uint_as_float(((unsigned)h) << 16);
}

// K1: blocks 0..31: Ex[b][f] = 2^(C2*(b1[f] + sum_k input[b][k]*W1[f*512+k])); w2n = -2*W2
//     blocks 32..95: split W1m into bf16 hi/lo arrays
__global__ __launch_bounds__(256) void k1_prep(const float* __restrict__ input,
                                               const float* __restrict__ W1,
                                               const float* __restrict__ b1,
                                               const float* __restrict__ W2,
                                               float* __restrict__ Ex,
                                               float* __restrict__ w2n,
                                               unsigned short* __restrict__ wh,
                                               unsigned short* __restrict__ wl) {
  if (blockIdx.x < BDIM) {
    const int b = blockIdx.x, f = threadIdx.x;
    const float* in = input + b * FDIM;
    const float* w  = W1 + (size_t)f * 512;
    float acc = b1[f];
    #pragma unroll 8
    for (int k = 0; k < FDIM; k += 4) {
      float4 iv = *(const float4*)(in + k);
      float4 wv = *(const float4*)(w + k);
      acc = fmaf(iv.x, wv.x, acc); acc = fmaf(iv.y, wv.y, acc);
      acc = fmaf(iv.z, wv.z, acc); acc = fmaf(iv.w, wv.w, acc);
    }
    Ex[b * FDIM + f] = __builtin_amdgcn_exp2f(acc * C2);
    if (b == 0) w2n[f] = -2.0f * W2[f];
  } else {
    int id = ((blockIdx.x - BDIM) * 256 + threadIdx.x) * 4;   // 0..65532
    int f = id >> 8, c = id & 255;
    float4 v = *(const float4*)(W1 + (size_t)f * 512 + 256 + c);
    float xs[4] = {v.x, v.y, v.z, v.w};
    #pragma unroll
    for (int e = 0; e < 4; ++e) {
      unsigned short h = f2bf(xs[e]);
      wh[id + e] = h;
      wl[id + e] = f2bf(xs[e] - bf2f(h));
    }
  }
}

// K23: fused k2_mfma + k3_score + out-copy. R2/R5 barrier structure (proven
// spill-free) but 1024-THREAD BLOCKS (16 waves): grid is fixed at 512 = 2
// blocks/CU, so wave occupancy doubles 16 -> 32 waves/CU (100%). MFMA work
// splits 16 ways: wave = (mh in 4 x 16-row, fq in 4 x 64-col), acc[4],
// 12 MFMA/step. Staging spreads over all 1024 threads. Phase 2: wave owns
// 2 b (ex stays SGPR-uniform), full 64-lane m map; NB/k45/ws unchanged.
__global__ __launch_bounds__(1024, 8) void k23_fused(const float* __restrict__ mem,
                                                     const unsigned short* __restrict__ wh,
                                                     const unsigned short* __restrict__ wl,
                                                     const float* __restrict__ Ex,
                                                     const float* __restrict__ w2n,
                                                     float* __restrict__ pmax,
                                                     float* __restrict__ psum,
                                                     int* __restrict__ parg,
                                                     float* __restrict__ out) {
  __shared__ __align__(16) char smem[51200];           // staging 51200; emT 34816 (aliased)
  unsigned short* AH = (unsigned short*)(smem);        // 64*40  = 5120 B
  unsigned short* AL = (unsigned short*)(smem + 5120);
  unsigned short* BH = (unsigned short*)(smem + 10240);// 256*40 = 20480 B
  unsigned short* BL = (unsigned short*)(smem + 30720);
  float* emT = (float*)smem;                           // per pass: [128][68] f32

  const int tid = threadIdx.x;
  const int lane = tid & 63, wid = tid >> 6;           // wid 0..15
  const int m0 = blockIdx.x * 64;
  const int rb = lane & 15, g8 = (lane >> 4) * 8;
  const int mh = wid & 3;        // m-16-subtile (16 rows)
  const int fq = wid >> 2;       // f-quarter (64 cols)

  f32x4 acc[4];
  #pragma unroll
  for (int j = 0; j < 4; ++j) acc[j] = (f32x4){0.f, 0.f, 0.f, 0.f};

  for (int s = 0; s < 8; ++s) {
    const int k0 = s * 32;
    __syncthreads();   // prior frag reads complete; LDS writable
    if (tid < 512) {   // stage A: 64 rows x 32 k (4 elems/thr), split hi/lo; out=mem
      int r = tid >> 3, c4 = (tid & 7) * 4;
      const float* mrow = mem + (size_t)(m0 + r) * 256 + k0 + c4;
      float4 a0 = *(const float4*)(mrow);
      *(float4*)(out + (size_t)(m0 + r) * 256 + k0 + c4) = a0;   // folded k0_copy
      float xs[4] = {a0.x, a0.y, a0.z, a0.w};
      ushort4v ahv, alv;
      #pragma unroll
      for (int e = 0; e < 4; ++e) {
        unsigned short h = f2bf(xs[e]);
        ahv[e] = h;
        alv[e] = f2bf(xs[e] - bf2f(h));
      }
      *(ushort4v*)&AH[r * 40 + c4] = ahv;
      *(ushort4v*)&AL[r * 40 + c4] = alv;
    } else {           // stage B: 256 rows x 32 k (pre-split, L2-resident), 2 iters/thr
      int t2 = tid - 512;
      #pragma unroll
      for (int q = 0; q < 2; ++q) {
        int id = q * 512 + t2, br = id >> 2, bc = (id & 3) * 8;
        *(uint4*)&BH[br * 40 + bc] = *(const uint4*)(wh + (size_t)br * 256 + k0 + bc);
        *(uint4*)&BL[br * 40 + bc] = *(const uint4*)(wl + (size_t)br * 256 + k0 + bc);
      }
    }
    __syncthreads();

    bf16x8 fah, fal, fbh[4], fbl[4];
    fah = *(const bf16x8*)&AH[(mh * 16 + rb) * 40 + g8];
    fal = *(const bf16x8*)&AL[(mh * 16 + rb) * 40 + g8];
    #pragma unroll
    for (int j = 0; j < 4; ++j) {
      fbh[j] = *(const bf16x8*)&BH[(fq * 64 + j * 16 + rb) * 40 + g8];
      fbl[j] = *(const bf16x8*)&BL[(fq * 64 + j * 16 + rb) * 40 + g8];
    }
    #pragma unroll
    for (int j = 0; j < 4; ++j) {
      acc[j] = __builtin_amdgcn_mfma_f32_16x16x32_bf16(fah, fbh[j], acc[j], 0, 0, 0);
      acc[j] = __builtin_amdgcn_mfma_f32_16x16x32_bf16(fah, fbl[j], acc[j], 0, 0, 0);
      acc[j] = __builtin_amdgcn_mfma_f32_16x16x32_bf16(fal, fbh[j], acc[j], 0, 0, 0);
    }
  }

  // Epilogue + phase 2 in TWO f-halves (emT [128][68] aliased over staging).
  // Pass h: waves with fq in {2h,2h+1} (wid>>3 == h) write their 128-f slab;
  // then ALL 16 waves score f in [128h, 128h+128), each wave owns 2 b.
  // D frag: f = fq*64 + j*16 + rb; m_local = mh*16 + (lane>>4)*4 + r.
  const int wuid = __builtin_amdgcn_readfirstlane(wid);  // 0..15
  const float* ex0 = Ex + (size_t)(wuid * 2 + 0) * FDIM;
  const float* ex1 = Ex + (size_t)(wuid * 2 + 1) * FDIM;
  float acc0 = 0.f, acc1 = 0.f;

  #pragma unroll
  for (int h = 0; h < 2; ++h) {
    __syncthreads();   // h=0: all frag reads done; h=1: pass-0 emT reads done
    if ((wid >> 3) == h) {
      #pragma unroll
      for (int j = 0; j < 4; ++j) {
        const int fl = (fq * 64 + j * 16 + rb) - h * 128;   // 0..127 local
        const int mloc = mh * 16 + (lane >> 4) * 4;
        float4 v;
        v.x = __builtin_amdgcn_exp2f(acc[j][0] * C2);
        v.y = __builtin_amdgcn_exp2f(acc[j][1] * C2);
        v.z = __builtin_amdgcn_exp2f(acc[j][2] * C2);
        v.w = __builtin_amdgcn_exp2f(acc[j][3] * C2);
        *(float4*)(emT + fl * 68 + mloc) = v;
      }
    }
    __syncthreads();

    // score this 128-f slab: 4-f groups share one rcp per b:
    //   sum_i w_i/u_i = [(w0u1+w1u0)u2u3 + (w2u3+w3u2)u0u1] / (u0u1u2u3)
    #pragma unroll 2
    for (int fl2 = 0; fl2 < 128; fl2 += 4) {
      const int fg = h * 128 + fl2;
      float e0 = emT[(fl2 + 0) * 68 + lane];
      float e1 = emT[(fl2 + 1) * 68 + lane];
      float e2 = emT[(fl2 + 2) * 68 + lane];
      float e3 = emT[(fl2 + 3) * 68 + lane];
      float w0 = w2n[fg + 0], w1 = w2n[fg + 1];   // uniform -> SGPR
      float w2 = w2n[fg + 2], w3 = w2n[fg + 3];
      #define SCORE4(exP, accV)                                          \
      {                                                                  \
        float u0 = fmaf(e0, exP[fg + 0], 1.f);                           \
        float u1 = fmaf(e1, exP[fg + 1], 1.f);                           \
        float u2 = fmaf(e2, exP[fg + 2], 1.f);                           \
        float u3 = fmaf(e3, exP[fg + 3], 1.f);                           \
        float p01 = u0 * u1, p23 = u2 * u3;                              \
        float den = p01 * p23;                                           \
        float t0 = fmaf(w1, u0, w0 * u1);                                \
        float t1 = fmaf(w3, u2, w2 * u3);                                \
        float num = fmaf(t1, p01, t0 * p23);                             \
        accV = fmaf(num, __builtin_amdgcn_rcpf(den), accV);              \
      }
      SCORE4(ex0, acc0)
      SCORE4(ex1, acc1)
      #undef SCORE4
    }
  }

  // wave reduce per owned b: max+argmax over 64 m lanes, then sumexp
  float accb[2] = {acc0, acc1};
  const int blk = blockIdx.x;
  #pragma unroll
  for (int bi = 0; bi < 2; ++bi) {
    float s = accb[bi]; int idx = m0 + lane;
    #pragma unroll
    for (int off = 32; off > 0; off >>= 1) {
      float so = __shfl_xor(s, off);
      int   io = __shfl_xor(idx, off);
      if (so > s || (so == s && io < idx)) { s = so; idx = io; }
    }
    float ex = __expf(accb[bi] - s);
    #pragma unroll
    for (int off = 32; off > 0; off >>= 1) ex += __shfl_xor(ex, off);
    if (lane == 0) {
      int b = wuid * 2 + bi;
      pmax[b * NB + blk] = s;
      psum[b * NB + blk] = ex;
      parg[b * NB + blk] = idx;
    }
  }
}

// K45: fused reduce + select + patch (single block, 16 waves).
// Wave w merges the 512 partials for b = 2w and 2w+1 (8 per lane + shfl
// tree), results in LDS; then dedup (winner = LARGEST masked b per slot);
// then patch winning rows out[ga[b]] = input[b] (32 threads per b).
__global__ __launch_bounds__(1024) void k45_finish(const float* __restrict__ pmax,
                                                   const float* __restrict__ psum,
                                                   const int* __restrict__ parg,
                                                   const float* __restrict__ thr_p,
                                                   const float* __restrict__ input,
                                                   float* __restrict__ out) {
  __shared__ float gm[BDIM], gs[BDIM];
  __shared__ int   ga[BDIM], wn[BDIM];
  const int tid = threadIdx.x, lane = tid & 63, w = tid >> 6;   // 16 waves
  #pragma unroll
  for (int half = 0; half < 2; ++half) {
    const int b = w * 2 + half;
    float cm = -3.0e38f, cs = 0.f; int ca = 0x7fffffff;
    #pragma unroll
    for (int t = 0; t < NB / 64; ++t) {
      int i = t * 64 + lane;
      float s = pmax[b * NB + i];
      float p = psum[b * NB + i];
      int   a = parg[b * NB + i];
      if (s > cm)      { cs = cs * __expf(cm - s) + p; cm = s; ca = a; }
      else if (s == cm){ cs += p; if (a < ca) ca = a; }
      else             { cs += p * __expf(s - cm); }
    }
    #pragma unroll
    for (int off = 32; off > 0; off >>= 1) {
      float om = __shfl_xor(cm, off);
      float os = __shfl_xor(cs, off);
      int   oa = __shfl_xor(ca, off);
      if (om > cm)      { cs = cs * __expf(cm - om) + os; cm = om; ca = oa; }
      else if (om == cm){ cs += os; if (oa < ca) ca = oa; }
      else              { cs += os * __expf(om - cm); }
    }
    if (lane == 0) { gm[b] = cm; gs[b] = cs; ga[b] = ca; }
  }
  __syncthreads();
  if (tid < BDIM) {
    const float thr = *thr_p;
    const int me = ga[tid];
    int w_ = (1.0f / gs[tid] > thr) ? 1 : 0;   // maxw = 1/sumexp
    if (w_) {
      for (int b2 = tid + 1; b2 < BDIM; ++b2)
        if ((1.0f / gs[b2] > thr) && ga[b2] == me) { w_ = 0; break; }
    }
    wn[tid] = w_;
  }
  __syncthreads();
  {
    const int b = tid >> 5, sub = tid & 31;
    if (wn[b]) {
      const int m = ga[b];
      *(float4*)(out + (size_t)m * 256 + sub * 8) =
          *(const float4*)(input + (size_t)b * 256 + sub * 8);
      *(float4*)(out + (size_t)m * 256 + sub * 8 + 4) =
          *(const float4*)(input + (size_t)b * 256 + sub * 8 + 4);
    }
  }
}

extern "C" void kernel_launch(void* const* d_in, const int* in_sizes, int n_in,
                              void* d_out, int out_size, void* d_ws, size_t ws_size,
                              hipStream_t stream) {
  const float* input  = (const float*)d_in[0];
  const float* memory = (const float*)d_in[1];
  const float* W1     = (const float*)d_in[2];
  const float* b1     = (const float*)d_in[3];
  const float* W2     = (const float*)d_in[4];
  // d_in[5] = b2: constant score shift, softmax/argmax/maxw invariant -> unused
  const float* thr    = (const float*)d_in[6];

  float* ws   = (float*)d_ws;
  float* Ex   = ws + WS_EX;
  float* w2n  = ws + WS_W2N;
  float* pmax = ws + WS_PMAX;
  float* psum = ws + WS_PSUM;
  int*   parg = (int*)(ws + WS_PARG);
  unsigned short* wh = (unsigned short*)(ws + WS_WH);
  unsigned short* wl = (unsigned short*)(ws + WS_WL);
  float* out  = (float*)d_out;

  hipLaunchKernelGGL(k1_prep,    dim3(BDIM + 64), dim3(256),  0, stream, input, W1, b1, W2, Ex, w2n, wh, wl);
  hipLaunchKernelGGL(k23_fused,  dim3(MDIM / 64), dim3(1024), 0, stream, memory, wh, wl, Ex, w2n, pmax, psum, parg, out);
  hipLaunchKernelGGL(k45_finish, dim3(1),         dim3(1024), 0, stream, pmax, psum, parg, thr, input, out);
}